// Round 1
// 96.433 us; speedup vs baseline: 1.0609x; 1.0609x over previous
//
#include <hip/hip_runtime.h>
#include <stdint.h>

#define NB 4
#define NN 512
#define NC 64
#define NH 128
#define NCO 64
#define MAXM 64          // fast-path cap on valid count (realistic max ~55)
#define MAXQ 16          // MAXM/4 float4 quads per channel

// mask dtype decode: int32 (w0==1), float32 (w0==0x3f800000), else packed bytes.
__device__ inline bool read_mask(const void* mp, int idx) {
    const int* ip = (const int*)mp;
    int w0 = ip[0];
    if (w0 == 1) return ip[idx] != 0;
    if (w0 == 0x3f800000) return ((const float*)mp)[idx] != 0.0f;
    return ((const unsigned char*)mp)[idx] != 0;
}

// Order-preserving float<->uint encoding so unsigned atomicMax == float max.
__device__ inline unsigned enc_key(float v) {
    unsigned b = __float_as_uint(v);
    return (b & 0x80000000u) ? ~b : (b | 0x80000000u);
}
__device__ inline float dec_key(unsigned k) {
    unsigned b = (k & 0x80000000u) ? (k & 0x7fffffffu) : ~k;
    return __uint_as_float(b);
}

// One block per row (2048 blocks, 4x occupancy vs old wave-per-row): each of
// the 4 waves owns 2 chunks of 64 columns; chunk neighbor-counts exchanged via
// LDS to build the global rank prefix. Blocks 0..63 also transpose W1/W2.
__global__ __launch_bounds__(256) void prep_kernel(
        const float* __restrict__ adj, const void* __restrict__ maskp,
        const float* __restrict__ W1, const float* __restrict__ W2,
        uint64_t* __restrict__ validbits, float* __restrict__ W1T,
        float* __restrict__ W2T, int dowt)
{
    __shared__ int s_m[8];
    int row = blockIdx.x;                // b*NN + i
    int tid = threadIdx.x, lane = tid & 63, wv = tid >> 6;
    int i = row & (NN - 1);
    const float* arow = adj + (size_t)row * NN;

    uint64_t bl0, bl1;
    {
        int j = (wv * 2) * 64 + lane;
        bool f = (j != i) && (arow[j] > 0.0f);
        bl0 = __ballot(f);
    }
    {
        int j = (wv * 2 + 1) * 64 + lane;
        bool f = (j != i) && (arow[j] > 0.0f);
        bl1 = __ballot(f);
    }
    if (lane == 0) {
        s_m[wv * 2]     = __popcll(bl0);
        s_m[wv * 2 + 1] = __popcll(bl1);
    }
    __syncthreads();

    int m = 0, prefix = 0;
    #pragma unroll
    for (int k = 0; k < 8; ++k) {
        int c = s_m[k];
        m += c;
        if (k < wv * 2) prefix += c;
    }
    int skip = (m > 10) ? ((m + 1) >> 1) : 1;   // ceil(m/2), K_DIL=2
    bool dodil = (skip > 1) && read_mask(maskp, row);
    int skip2 = skip * 2;
    uint64_t lanelt = (1ull << lane) - 1ull;
    {
        int rank1 = prefix + __popcll(bl0 & lanelt) + 1;
        bool f = (bl0 >> lane) & 1ull;
        // (rank % skip)==0 <=> rank==skip || rank==2*skip  (rank <= m <= 2*skip)
        bool keep = f && !(dodil && (rank1 == skip || rank1 == skip2));
        uint64_t vb = __ballot(keep);
        if (lane == 0) validbits[(size_t)row * 8 + wv * 2] = vb;
        prefix += __popcll(bl0);
    }
    {
        int rank1 = prefix + __popcll(bl1 & lanelt) + 1;
        bool f = (bl1 >> lane) & 1ull;
        bool keep = f && !(dodil && (rank1 == skip || rank1 == skip2));
        uint64_t vb = __ballot(keep);
        if (lane == 0) validbits[(size_t)row * 8 + wv * 2 + 1] = vb;
    }

    if (dowt) {
        int e = blockIdx.x * 256 + threadIdx.x;
        if (e < 8192) {                       // W1T[k][c] = W1[c][k]
            int k = e >> 6, c = e & 63;
            W1T[e] = W1[c * NH + k];
        } else if (e < 16384) {               // W2T[o][k] = W2[k][o]
            int e2 = e - 8192;
            int o = e2 >> 7, k = e2 & 127;
            W2T[e2] = W2[k * NCO + o];
        }
    }
}

// One 256-thread block per row. LDS ~18.6 KB -> 8 blocks/CU (whole grid
// resident in one round). MLP scratch overlays the staging buffer post-P4.
template<bool USE_WT>
__global__ __launch_bounds__(256, 8) void fused_kernel(
        const float* __restrict__ x,
        const void* __restrict__ maskp,
        const float* __restrict__ W1,
        const float* __restrict__ b1,
        const float* __restrict__ W2,
        const float* __restrict__ b2,
        const uint64_t* __restrict__ validbits,
        const float* __restrict__ W1T,
        const float* __restrict__ W2T,
        float* __restrict__ out)
{
    int row = blockIdx.x;                // b*NN + i
    int b = row >> 9, i = row & (NN - 1);
    int tid = threadIdx.x, lane = tid & 63, wv = tid >> 6;
    float* outp = out + (size_t)row * NCO;

    if (!read_mask(maskp, row)) {        // masked row: explicit zeros (out poisoned)
        if (tid < NCO) outp[tid] = 0.0f;
        return;
    }

    __shared__ float4 s_q4[NC * MAXQ];   // 16 KB staging; reused as MLP scratch
    __shared__ uint16_t s_idx[NN];       // valid list (unordered); 1 KB
    __shared__ unsigned s_qk[NC * 6];    // per-(channel,target) max-key; 1.5 KB
    __shared__ uint64_t s_vb[8];         // row i's validbits
    __shared__ int s_cnt;

    float xval = (tid < NC) ? x[(size_t)row * NC + tid] : 0.0f;  // prefetch
    if (tid < 8) s_vb[tid] = validbits[(size_t)row * 8 + tid];
    if (tid == 0) { s_cnt = 1; s_idx[0] = (uint16_t)i; }         // self at slot 0
    __syncthreads();

    // ---- P2: valid(i,j) = vb_i[j] && vb_j[i]; wave-ballot compaction ----
    int ic = i >> 6;
    uint64_t imask = 1ull << (i & 63);
    uint64_t lanelt = (1ull << lane) - 1ull;
    #pragma unroll
    for (int it = 0; it < 2; ++it) {
        int j = tid + it * 256;
        bool hit = false;
        if ((s_vb[j >> 6] >> (j & 63)) & 1ull) {
            uint64_t wJ = validbits[((size_t)(b * NN + j)) * 8 + ic];
            hit = (wJ & imask) != 0;
        }
        uint64_t bal = __ballot(hit);
        int base = 0;
        if (lane == 0 && bal) base = atomicAdd(&s_cnt, __popcll(bal));
        base = __shfl(base, 0);
        if (hit) s_idx[base + __popcll(bal & lanelt)] = (uint16_t)j;
    }
    __syncthreads();
    int m = s_cnt;                       // >= 1 (self-loop)

    // ---- P3: stage x transposed [c][quad], XOR-16 swizzled, tail = +huge ----
    bool fast = (m <= MAXM);
    int mq = (m + 3) >> 2;
    float* sv = (float*)s_q4;
    if (fast) {
        int mq4 = mq << 2;
        for (int j = wv; j < mq4; j += 4) {          // wave wv owns neighbor j
            float v = 3.0e38f;
            if (j < m) v = x[((size_t)(b * NN + s_idx[j])) * NC + lane];
            int slot = (j >> 2) ^ (lane & 15);
            sv[lane * 64 + slot * 4 + (j & 3)] = v;
        }
    }
    // init max-keys (encoded 0 == smallest) before the P4 barrier
    if (tid < NC * 6 / 2) { s_qk[tid] = 0u; s_qk[tid + NC * 3] = 0u; }
    __syncthreads();

    // ---- quantile target ranks (torch 'linear'): tr = {lo0,hi0,lo1,hi1,lo2,hi2}
    float mf = (float)m;
    const float taus[3] = {0.25f, 0.5f, 0.75f};
    const float wts[3]  = {0.25f, 0.5f, 0.25f};
    int tr[6];
    float tfrac[3];
    #pragma unroll
    for (int t = 0; t < 3; ++t) {
        float pos = taus[t] * (mf - 1.0f);
        float fl = floorf(pos);
        tr[2 * t]     = (int)fl;
        tr[2 * t + 1] = (int)ceilf(pos);
        tfrac[t] = pos - fl;
    }

    // ---- P4: rank selection via max-identity: ans(t) = max{v : rs(v) <= t}.
    // Only strict-less counts needed (eq-counting eliminated). Padding (3e38)
    // self-filters (rs >= m > t). ----
    if (fast) {
        const float4* basep = s_q4 + lane * MAXQ;
        int sw = lane & 15;
        float vmax[6];
        #pragma unroll
        for (int t = 0; t < 6; ++t) vmax[t] = -3.0e38f;
        for (int ch = wv; ch < mq; ch += 4) {
            float4 q1 = basep[ch ^ sw];
            int rs0 = 0, rs1 = 0, rs2 = 0, rs3 = 0;
            for (int jq = 0; jq < mq; ++jq) {
                float4 v = basep[jq ^ sw];
                rs0 += (v.x < q1.x) + (v.y < q1.x) + (v.z < q1.x) + (v.w < q1.x);
                rs1 += (v.x < q1.y) + (v.y < q1.y) + (v.z < q1.y) + (v.w < q1.y);
                rs2 += (v.x < q1.z) + (v.y < q1.z) + (v.z < q1.z) + (v.w < q1.z);
                rs3 += (v.x < q1.w) + (v.y < q1.w) + (v.z < q1.w) + (v.w < q1.w);
            }
            float qe[4] = {q1.x, q1.y, q1.z, q1.w};
            int rsa[4] = {rs0, rs1, rs2, rs3};
            #pragma unroll
            for (int q = 0; q < 4; ++q) {
                #pragma unroll
                for (int t = 0; t < 6; ++t)
                    vmax[t] = fmaxf(vmax[t], (rsa[q] <= tr[t]) ? qe[q] : -3.0e38f);
            }
        }
        unsigned* qk = s_qk + lane * 6;
        #pragma unroll
        for (int t = 0; t < 6; ++t) atomicMax(qk + t, enc_key(vmax[t]));
    } else if (tid < NC) {
        // correctness fallback for m > MAXM (doesn't trigger on bench data)
        const float* xb = x + (size_t)b * NN * NC;
        int c = tid;
        float vmax[6];
        #pragma unroll
        for (int t = 0; t < 6; ++t) vmax[t] = -3.0e38f;
        for (int j1 = 0; j1 < m; ++j1) {
            float v1 = xb[(size_t)s_idx[j1] * NC + c];
            int rs = 0;
            for (int j2 = 0; j2 < m; ++j2)
                rs += xb[(size_t)s_idx[j2] * NC + c] < v1;
            #pragma unroll
            for (int t = 0; t < 6; ++t)
                vmax[t] = fmaxf(vmax[t], (rs <= tr[t]) ? v1 : -3.0e38f);
        }
        unsigned* qk = s_qk + c * 6;
        #pragma unroll
        for (int t = 0; t < 6; ++t) atomicMax(qk + t, enc_key(vmax[t]));
    }
    __syncthreads();

    // ---- MLP scratch overlays the (now dead) staging buffer ----
    float* s_mlp  = (float*)s_q4;
    float* s_out  = s_mlp;               // [0,64)
    float* s_h    = s_mlp + 64;          // [64,192)
    float* s_hp   = s_mlp + 256;         // [256,512)
    float* s_part = s_mlp + 512;         // [512,768)

    if (tid < NC) {                      // out = x + sum wt * lerp(q_lo, q_hi)
        float agg = 0.0f;
        #pragma unroll
        for (int t = 0; t < 3; ++t) {
            float qlo = dec_key(s_qk[tid * 6 + 2 * t]);
            float qhi = dec_key(s_qk[tid * 6 + 2 * t + 1]);
            agg += wts[t] * (qlo * (1.0f - tfrac[t]) + qhi * tfrac[t]);
        }
        s_out[tid] = xval + agg;
    }
    __syncthreads();

    // ---- MLP1: 256 threads = 128 k x 2 cc-halves ----
    {
        int k = tid & 127, g = tid >> 7;
        float acc = 0.0f;
        if (USE_WT) {
            const float4* w = (const float4*)(W1T + k * 64 + g * 32);
            #pragma unroll
            for (int q = 0; q < 8; ++q) {
                float4 wq = w[q];
                int cc = g * 32 + q * 4;
                acc += wq.x * s_out[cc] + wq.y * s_out[cc + 1]
                     + wq.z * s_out[cc + 2] + wq.w * s_out[cc + 3];
            }
        } else {
            for (int cc = g * 32; cc < g * 32 + 32; ++cc)
                acc += s_out[cc] * W1[cc * NH + k];
        }
        s_hp[g * NH + k] = acc;
    }
    __syncthreads();
    if (tid < NH) {
        float a = s_hp[tid] + s_hp[NH + tid] + b1[tid];
        s_h[tid] = a > 0.0f ? a : 0.0f;
    }
    __syncthreads();

    // ---- MLP2: 256 threads = 64 o x 4 k-quarters ----
    {
        int o = tid & 63, g = tid >> 6;
        float acc = 0.0f;
        if (USE_WT) {
            const float4* w = (const float4*)(W2T + o * 128 + g * 32);
            #pragma unroll
            for (int q = 0; q < 8; ++q) {
                float4 wq = w[q];
                int k = g * 32 + q * 4;
                acc += wq.x * s_h[k] + wq.y * s_h[k + 1]
                     + wq.z * s_h[k + 2] + wq.w * s_h[k + 3];
            }
        } else {
            for (int k = g * 32; k < g * 32 + 32; ++k)
                acc += s_h[k] * W2[k * NCO + o];
        }
        s_part[g * NCO + o] = acc;
    }
    __syncthreads();
    if (tid < NCO)
        outp[tid] = s_part[tid] + s_part[64 + tid] + s_part[128 + tid]
                  + s_part[192 + tid] + b2[tid];
}

extern "C" void kernel_launch(void* const* d_in, const int* in_sizes, int n_in,
                              void* d_out, int out_size, void* d_ws, size_t ws_size,
                              hipStream_t stream) {
    const float* x   = (const float*)d_in[0];
    const float* adj = (const float*)d_in[1];
    const void* mask = d_in[2];
    const float* W1  = (const float*)d_in[3];
    const float* b1  = (const float*)d_in[4];
    const float* W2  = (const float*)d_in[5];
    const float* b2  = (const float*)d_in[6];
    float* out = (float*)d_out;

    uint64_t* validbits = (uint64_t*)d_ws;               // 128 KB
    float* W1T = (float*)((char*)d_ws + 131072);         // 32 KB
    float* W2T = W1T + 8192;                             // 32 KB
    int dowt = (ws_size >= 196608) ? 1 : 0;

    prep_kernel<<<NB * NN, 256, 0, stream>>>(adj, mask, W1, W2, validbits, W1T, W2T, dowt);
    if (dowt)
        fused_kernel<true><<<NB * NN, 256, 0, stream>>>(
            x, mask, W1, b1, W2, b2, validbits, W1T, W2T, out);
    else
        fused_kernel<false><<<NB * NN, 256, 0, stream>>>(
            x, mask, W1, b1, W2, b2, validbits, W1T, W2T, out);
}

// Round 2
// 95.576 us; speedup vs baseline: 1.0705x; 1.0090x over previous
//
#include <hip/hip_runtime.h>
#include <stdint.h>

#define NB 4
#define NN 512
#define NC 64
#define NH 128
#define NCO 64
#define MAXM 64          // fast-path cap on valid count (realistic max ~55)
#define MAXQ 16          // MAXM/4 float4 quads per channel

// mask dtype decode: int32 (w0==1), float32 (w0==0x3f800000), else packed bytes.
__device__ inline bool read_mask(const void* mp, int idx) {
    const int* ip = (const int*)mp;
    int w0 = ip[0];
    if (w0 == 1) return ip[idx] != 0;
    if (w0 == 0x3f800000) return ((const float*)mp)[idx] != 0.0f;
    return ((const unsigned char*)mp)[idx] != 0;
}

// Order-preserving float<->uint encoding so unsigned atomicMax == float max.
__device__ inline unsigned enc_key(float v) {
    unsigned b = __float_as_uint(v);
    return (b & 0x80000000u) ? ~b : (b | 0x80000000u);
}
__device__ inline float dec_key(unsigned k) {
    unsigned b = (k & 0x80000000u) ? (k & 0x7fffffffu) : ~k;
    return __uint_as_float(b);
}

// One block per row (2048 blocks): each of the 4 waves owns 2 chunks of 64
// columns; chunk neighbor-counts exchanged via LDS to build the global rank
// prefix. Blocks 0..63 also transpose W1/W2.
__global__ __launch_bounds__(256) void prep_kernel(
        const float* __restrict__ adj, const void* __restrict__ maskp,
        const float* __restrict__ W1, const float* __restrict__ W2,
        uint64_t* __restrict__ validbits, float* __restrict__ W1T,
        float* __restrict__ W2T, int dowt)
{
    __shared__ int s_m[8];
    int row = blockIdx.x;                // b*NN + i
    int tid = threadIdx.x, lane = tid & 63, wv = tid >> 6;
    int i = row & (NN - 1);
    const float* arow = adj + (size_t)row * NN;

    uint64_t bl0, bl1;
    {
        int j = (wv * 2) * 64 + lane;
        bool f = (j != i) && (arow[j] > 0.0f);
        bl0 = __ballot(f);
    }
    {
        int j = (wv * 2 + 1) * 64 + lane;
        bool f = (j != i) && (arow[j] > 0.0f);
        bl1 = __ballot(f);
    }
    if (lane == 0) {
        s_m[wv * 2]     = __popcll(bl0);
        s_m[wv * 2 + 1] = __popcll(bl1);
    }
    __syncthreads();

    int m = 0, prefix = 0;
    #pragma unroll
    for (int k = 0; k < 8; ++k) {
        int c = s_m[k];
        m += c;
        if (k < wv * 2) prefix += c;
    }
    int skip = (m > 10) ? ((m + 1) >> 1) : 1;   // ceil(m/2), K_DIL=2
    bool dodil = (skip > 1) && read_mask(maskp, row);
    int skip2 = skip * 2;
    uint64_t lanelt = (1ull << lane) - 1ull;
    {
        int rank1 = prefix + __popcll(bl0 & lanelt) + 1;
        bool f = (bl0 >> lane) & 1ull;
        // (rank % skip)==0 <=> rank==skip || rank==2*skip  (rank <= m <= 2*skip)
        bool keep = f && !(dodil && (rank1 == skip || rank1 == skip2));
        uint64_t vb = __ballot(keep);
        if (lane == 0) validbits[(size_t)row * 8 + wv * 2] = vb;
        prefix += __popcll(bl0);
    }
    {
        int rank1 = prefix + __popcll(bl1 & lanelt) + 1;
        bool f = (bl1 >> lane) & 1ull;
        bool keep = f && !(dodil && (rank1 == skip || rank1 == skip2));
        uint64_t vb = __ballot(keep);
        if (lane == 0) validbits[(size_t)row * 8 + wv * 2 + 1] = vb;
    }

    if (dowt) {
        int e = blockIdx.x * 256 + threadIdx.x;
        if (e < 8192) {                       // W1T[k][c] = W1[c][k]
            int k = e >> 6, c = e & 63;
            W1T[e] = W1[c * NH + k];
        } else if (e < 16384) {               // W2T[o][k] = W2[k][o]
            int e2 = e - 8192;
            int o = e2 >> 7, k = e2 & 127;
            W2T[e2] = W2[k * NCO + o];
        }
    }
}

// One 256-thread block per row. LDS ~18.6 KB -> 8 blocks/CU (whole grid
// resident in one round). MLP scratch overlays the staging buffer post-P4.
template<bool USE_WT>
__global__ __launch_bounds__(256, 8) void fused_kernel(
        const float* __restrict__ x,
        const void* __restrict__ maskp,
        const float* __restrict__ W1,
        const float* __restrict__ b1,
        const float* __restrict__ W2,
        const float* __restrict__ b2,
        const uint64_t* __restrict__ validbits,
        const float* __restrict__ W1T,
        const float* __restrict__ W2T,
        float* __restrict__ out)
{
    int row = blockIdx.x;                // b*NN + i
    int b = row >> 9, i = row & (NN - 1);
    int tid = threadIdx.x, lane = tid & 63, wv = tid >> 6;
    float* outp = out + (size_t)row * NCO;

    if (!read_mask(maskp, row)) {        // masked row: explicit zeros (out poisoned)
        if (tid < NCO) outp[tid] = 0.0f;
        return;
    }

    __shared__ float4 s_q4[NC * MAXQ];   // 16 KB staging; reused as MLP scratch
    __shared__ uint16_t s_idx[NN];       // valid list (unordered); 1 KB
    __shared__ unsigned s_qk[NC * 6];    // per-(channel,target) max-key; 1.5 KB
    __shared__ uint64_t s_vb[8];         // row i's validbits
    __shared__ int s_cnt;

    float xval = (tid < NC) ? x[(size_t)row * NC + tid] : 0.0f;  // prefetch
    if (tid < 8) s_vb[tid] = validbits[(size_t)row * 8 + tid];
    if (tid == 0) { s_cnt = 1; s_idx[0] = (uint16_t)i; }         // self at slot 0
    __syncthreads();

    // ---- P2: valid(i,j) = vb_i[j] && vb_j[i]; wave-ballot compaction ----
    int ic = i >> 6;
    uint64_t imask = 1ull << (i & 63);
    uint64_t lanelt = (1ull << lane) - 1ull;
    #pragma unroll
    for (int it = 0; it < 2; ++it) {
        int j = tid + it * 256;
        bool hit = false;
        if ((s_vb[j >> 6] >> (j & 63)) & 1ull) {
            uint64_t wJ = validbits[((size_t)(b * NN + j)) * 8 + ic];
            hit = (wJ & imask) != 0;
        }
        uint64_t bal = __ballot(hit);
        int base = 0;
        if (lane == 0 && bal) base = atomicAdd(&s_cnt, __popcll(bal));
        base = __shfl(base, 0);
        if (hit) s_idx[base + __popcll(bal & lanelt)] = (uint16_t)j;
    }
    __syncthreads();
    int m = s_cnt;                       // >= 1 (self-loop)

    // ---- P3: stage x transposed [c][quad], XOR-16 swizzled, tail = +huge.
    // float4 form: 16 lanes cover one neighbor row, 4 neighbors/wave-iter. ----
    bool fast = (m <= MAXM);
    int mq = (m + 3) >> 2;
    float* sv = (float*)s_q4;
    if (fast) {
        int n = lane >> 4;               // neighbor-within-quad
        int cc = (lane & 15) * 4;        // channel base
        for (int jq = wv; jq < mq; jq += 4) {    // wave wv owns neighbor quad jq
            int j = jq * 4 + n;
            float4 v = make_float4(3.0e38f, 3.0e38f, 3.0e38f, 3.0e38f);
            if (j < m)
                v = *(const float4*)&x[((size_t)(b * NN + s_idx[j])) * NC + cc];
            float vv[4] = {v.x, v.y, v.z, v.w};
            #pragma unroll
            for (int k = 0; k < 4; ++k) {        // scatter-transpose into swizzle
                int c = cc + k;
                int slot = jq ^ (c & 15);
                sv[c * 64 + slot * 4 + n] = vv[k];
            }
        }
    }
    // init max-keys (encoded 0 == smallest) before the P4 barrier
    if (tid < NC * 6 / 2) { s_qk[tid] = 0u; s_qk[tid + NC * 3] = 0u; }
    __syncthreads();

    // ---- quantile target ranks (torch 'linear'): tr = {lo0,hi0,lo1,hi1,lo2,hi2}
    float mf = (float)m;
    const float taus[3] = {0.25f, 0.5f, 0.75f};
    const float wts[3]  = {0.25f, 0.5f, 0.25f};
    int tr[6];
    float tfrac[3];
    #pragma unroll
    for (int t = 0; t < 3; ++t) {
        float pos = taus[t] * (mf - 1.0f);
        float fl = floorf(pos);
        tr[2 * t]     = (int)fl;
        tr[2 * t + 1] = (int)ceilf(pos);
        tfrac[t] = pos - fl;
    }

    // ---- P4: rank selection via max-identity: ans(t) = max{v : rs(v) <= t}.
    // Only strict-less counts needed. Padding (3e38) self-filters (rs >= m > t).
    if (fast) {
        const float4* basep = s_q4 + lane * MAXQ;
        int sw = lane & 15;
        float vmax[6];
        #pragma unroll
        for (int t = 0; t < 6; ++t) vmax[t] = -3.0e38f;
        for (int ch = wv; ch < mq; ch += 4) {
            float4 q1 = basep[ch ^ sw];
            int rs0 = 0, rs1 = 0, rs2 = 0, rs3 = 0;
            for (int jq = 0; jq < mq; ++jq) {
                float4 v = basep[jq ^ sw];
                rs0 += (v.x < q1.x) + (v.y < q1.x) + (v.z < q1.x) + (v.w < q1.x);
                rs1 += (v.x < q1.y) + (v.y < q1.y) + (v.z < q1.y) + (v.w < q1.y);
                rs2 += (v.x < q1.z) + (v.y < q1.z) + (v.z < q1.z) + (v.w < q1.z);
                rs3 += (v.x < q1.w) + (v.y < q1.w) + (v.z < q1.w) + (v.w < q1.w);
            }
            float qe[4] = {q1.x, q1.y, q1.z, q1.w};
            int rsa[4] = {rs0, rs1, rs2, rs3};
            #pragma unroll
            for (int q = 0; q < 4; ++q) {
                #pragma unroll
                for (int t = 0; t < 6; ++t)
                    vmax[t] = fmaxf(vmax[t], (rsa[q] <= tr[t]) ? qe[q] : -3.0e38f);
            }
        }
        unsigned* qk = s_qk + lane * 6;
        #pragma unroll
        for (int t = 0; t < 6; ++t) atomicMax(qk + t, enc_key(vmax[t]));
    } else if (tid < NC) {
        // correctness fallback for m > MAXM (doesn't trigger on bench data)
        const float* xb = x + (size_t)b * NN * NC;
        int c = tid;
        float vmax[6];
        #pragma unroll
        for (int t = 0; t < 6; ++t) vmax[t] = -3.0e38f;
        for (int j1 = 0; j1 < m; ++j1) {
            float v1 = xb[(size_t)s_idx[j1] * NC + c];
            int rs = 0;
            for (int j2 = 0; j2 < m; ++j2)
                rs += xb[(size_t)s_idx[j2] * NC + c] < v1;
            #pragma unroll
            for (int t = 0; t < 6; ++t)
                vmax[t] = fmaxf(vmax[t], (rs <= tr[t]) ? v1 : -3.0e38f);
        }
        unsigned* qk = s_qk + c * 6;
        #pragma unroll
        for (int t = 0; t < 6; ++t) atomicMax(qk + t, enc_key(vmax[t]));
    }
    __syncthreads();

    // ---- MLP scratch overlays the (now dead) staging buffer ----
    float* s_mlp  = (float*)s_q4;
    float* s_out  = s_mlp;               // [0,64)
    float* s_h    = s_mlp + 64;          // [64,192)
    float* s_part = s_mlp + 192;         // [192,448)

    if (tid < NC) {                      // out = x + sum wt * lerp(q_lo, q_hi)
        float agg = 0.0f;
        #pragma unroll
        for (int t = 0; t < 3; ++t) {
            float qlo = dec_key(s_qk[tid * 6 + 2 * t]);
            float qhi = dec_key(s_qk[tid * 6 + 2 * t + 1]);
            agg += wts[t] * (qlo * (1.0f - tfrac[t]) + qhi * tfrac[t]);
        }
        s_out[tid] = xval + agg;
    }
    __syncthreads();

    // ---- MLP1: 128 threads, full 64-dot each, relu fused (no partial split) ----
    if (tid < NH) {
        float acc = b1[tid];
        if (USE_WT) {
            const float4* w = (const float4*)(W1T + tid * 64);
            const float4* so = (const float4*)s_out;
            #pragma unroll
            for (int q = 0; q < 16; ++q) {
                float4 wq = w[q];
                float4 sq = so[q];
                acc += wq.x * sq.x + wq.y * sq.y + wq.z * sq.z + wq.w * sq.w;
            }
        } else {
            for (int cc = 0; cc < NC; ++cc)
                acc += s_out[cc] * W1[cc * NH + tid];
        }
        s_h[tid] = acc > 0.0f ? acc : 0.0f;
    }
    __syncthreads();

    // ---- MLP2: 256 threads = 64 o x 4 k-quarters ----
    {
        int o = tid & 63, g = tid >> 6;
        float acc = 0.0f;
        if (USE_WT) {
            const float4* w = (const float4*)(W2T + o * 128 + g * 32);
            #pragma unroll
            for (int q = 0; q < 8; ++q) {
                float4 wq = w[q];
                int k = g * 32 + q * 4;
                acc += wq.x * s_h[k] + wq.y * s_h[k + 1]
                     + wq.z * s_h[k + 2] + wq.w * s_h[k + 3];
            }
        } else {
            for (int k = g * 32; k < g * 32 + 32; ++k)
                acc += s_h[k] * W2[k * NCO + o];
        }
        s_part[g * NCO + o] = acc;
    }
    __syncthreads();
    if (tid < NCO)
        outp[tid] = s_part[tid] + s_part[64 + tid] + s_part[128 + tid]
                  + s_part[192 + tid] + b2[tid];
}

extern "C" void kernel_launch(void* const* d_in, const int* in_sizes, int n_in,
                              void* d_out, int out_size, void* d_ws, size_t ws_size,
                              hipStream_t stream) {
    const float* x   = (const float*)d_in[0];
    const float* adj = (const float*)d_in[1];
    const void* mask = d_in[2];
    const float* W1  = (const float*)d_in[3];
    const float* b1  = (const float*)d_in[4];
    const float* W2  = (const float*)d_in[5];
    const float* b2  = (const float*)d_in[6];
    float* out = (float*)d_out;

    uint64_t* validbits = (uint64_t*)d_ws;               // 128 KB
    float* W1T = (float*)((char*)d_ws + 131072);         // 32 KB
    float* W2T = W1T + 8192;                             // 32 KB
    int dowt = (ws_size >= 196608) ? 1 : 0;

    prep_kernel<<<NB * NN, 256, 0, stream>>>(adj, mask, W1, W2, validbits, W1T, W2T, dowt);
    if (dowt)
        fused_kernel<true><<<NB * NN, 256, 0, stream>>>(
            x, mask, W1, b1, W2, b2, validbits, W1T, W2T, out);
    else
        fused_kernel<false><<<NB * NN, 256, 0, stream>>>(
            x, mask, W1, b1, W2, b2, validbits, W1T, W2T, out);
}